// Round 1
// baseline (363.388 us; speedup 1.0000x reference)
//
#include <hip/hip_runtime.h>

// PE constants:
//   w_j   = 10000^(-j/256) = exp2f(PE_C2 * j),  PE_C2 = -log2(10000)/256
//   angle = i * w_j ;  pe[i, 2j] = sin(angle), pe[i, 2j+1] = cos(angle)
// Columns 510/511 stay zero (reference uses n_pairs = 255).
#define PE_C2 (-0.051905126482615034f)

// One float4 of output per thread. DEPTH=512 -> 128 float4 per row.
// idx = row*128 + v ; a 64-lane wave covers half a row: token load is
// wave-uniform, emb-row read is 1024B contiguous, store fully coalesced.
__global__ __launch_bounds__(256) void pe_gather_kernel(
    const int* __restrict__ token_ids,
    const float4* __restrict__ emb,       // emb_table viewed as [VOCAB][128] float4
    float4* __restrict__ out,             // [SEQ][128] float4
    int total)                            // SEQ * 128
{
    const int idx = blockIdx.x * blockDim.x + threadIdx.x;
    if (idx >= total) return;

    const int row = idx >> 7;     // token position i
    const int v   = idx & 127;    // float4 index within the row

    const int tok = token_ids[row];
    const float4 e = emb[(long long)tok * 128 + v];

    const float fi = (float)row;

    // first pair: j0 = 2v  (always < 255)
    const float w0 = exp2f(PE_C2 * (float)(2 * v));
    float s0, c0;
    __sincosf(fi * w0, &s0, &c0);

    float4 r;
    r.x = e.x + s0;
    r.y = e.y + c0;

    if (v < 127) {
        // second pair: j1 = 2v+1 (< 255)
        const float w1 = exp2f(PE_C2 * (float)(2 * v + 1));
        float s1, c1;
        __sincosf(fi * w1, &s1, &c1);
        r.z = e.z + s1;
        r.w = e.w + c1;
    } else {
        // j1 = 255 -> out of range in reference -> pe = 0
        r.z = e.z;
        r.w = e.w;
    }

    out[idx] = r;
}

extern "C" void kernel_launch(void* const* d_in, const int* in_sizes, int n_in,
                              void* d_out, int out_size, void* d_ws, size_t ws_size,
                              hipStream_t stream) {
    const int*   token_ids = (const int*)d_in[0];
    const float* emb_table = (const float*)d_in[1];
    float*       out       = (float*)d_out;

    const int seq   = in_sizes[0];        // 131072
    const int total = seq * 128;          // float4 count = seq * 512 / 4

    const int block = 256;
    const int grid  = (total + block - 1) / block;

    pe_gather_kernel<<<grid, block, 0, stream>>>(
        token_ids, (const float4*)emb_table, (float4*)out, total);
}

// Round 3
// 356.760 us; speedup vs baseline: 1.0186x; 1.0186x over previous
//
#include <hip/hip_runtime.h>

// PE constants:
//   w_j   = 10000^(-j/256) = exp2f(PE_C2 * j),  PE_C2 = -log2(10000)/256
//   angle = i * w_j ;  pe[i, 2j] = sin(angle), pe[i, 2j+1] = cos(angle)
// Columns 510/511 stay zero (reference uses n_pairs = 255).
// NOTE (R2 post-mortem): do NOT derive w_{2v+1} = w_{2v} * const with a
// hand-computed ratio — a 5.7e-6 constant error became a 0.73 absmax blowup
// at i=131071. Two exp2f calls are effectively free (trans pipe idle).
#define PE_C2 (-0.051905126482615034f)

typedef float vfloat4 __attribute__((ext_vector_type(4)));

// One float4 of output per thread. DEPTH=512 -> 128 float4 per row.
// idx = row*128 + v ; a 64-lane wave covers half a row: token load is
// wave-uniform, emb-row read is 1024B contiguous, store fully coalesced.
// Output stores are NON-TEMPORAL: the 268MB write-once stream must not
// evict the 103MB gather table from L2/L3 (table fits in the 256MB
// Infinity Cache if we don't thrash it).
__global__ __launch_bounds__(256) void pe_gather_kernel(
    const int* __restrict__ token_ids,
    const vfloat4* __restrict__ emb,      // emb_table viewed as [VOCAB][128] float4
    vfloat4* __restrict__ out,            // [SEQ][128] float4
    int total)                            // SEQ * 128
{
    const int idx = blockIdx.x * blockDim.x + threadIdx.x;
    if (idx >= total) return;

    const int row = idx >> 7;     // token position i
    const int v   = idx & 127;    // float4 index within the row

    const int tok = token_ids[row];
    const vfloat4 e = emb[(long long)tok * 128 + v];

    const float fi = (float)row;

    // first pair: j0 = 2v  (always < 255)
    const float w0 = exp2f(PE_C2 * (float)(2 * v));
    float s0, c0;
    __sincosf(fi * w0, &s0, &c0);

    vfloat4 r;
    r.x = e.x + s0;
    r.y = e.y + c0;

    if (v < 127) {
        // second pair: j1 = 2v+1 (< 255)
        const float w1 = exp2f(PE_C2 * (float)(2 * v + 1));
        float s1, c1;
        __sincosf(fi * w1, &s1, &c1);
        r.z = e.z + s1;
        r.w = e.w + c1;
    } else {
        // j1 = 255 -> out of range in reference -> pe = 0
        r.z = e.z;
        r.w = e.w;
    }

    __builtin_nontemporal_store(r, &out[idx]);
}

extern "C" void kernel_launch(void* const* d_in, const int* in_sizes, int n_in,
                              void* d_out, int out_size, void* d_ws, size_t ws_size,
                              hipStream_t stream) {
    const int*   token_ids = (const int*)d_in[0];
    const float* emb_table = (const float*)d_in[1];

    const int seq   = in_sizes[0];        // 131072
    const int total = seq * 128;          // float4 count = seq * 512 / 4

    const int block = 256;
    const int grid  = (total + block - 1) / block;

    pe_gather_kernel<<<grid, block, 0, stream>>>(
        token_ids, (const vfloat4*)emb_table, (vfloat4*)d_out, total);
}

// Round 4
// 351.242 us; speedup vs baseline: 1.0346x; 1.0157x over previous
//
#include <hip/hip_runtime.h>

// PE constants:
//   w_j   = 10000^(-j/256) = exp2f(PE_C2 * j),  PE_C2 = -log2(10000)/256
//   angle = i * w_j ;  pe[i, 2j] = sin(angle), pe[i, 2j+1] = cos(angle)
// Columns 510/511 stay zero (reference uses n_pairs = 255).
// NOTE (R2 post-mortem): do NOT replace the second exp2f with a hand-derived
// ratio constant — a 5.7e-6 constant error became 0.73 absmax at i=131071.
#define PE_C2 (-0.051905126482615034f)

typedef float vfloat4 __attribute__((ext_vector_type(4)));

#define NBLK   2048
#define NTHR   256
#define NTHREADS (NBLK * NTHR)          // 524288 threads, = 4096 rows per sweep
#define ROWS_PER_SWEEP (NTHREADS / 128) // 4096

// Persistent grid-stride kernel. Each thread owns one column-slot v (const
// across iterations since the sweep stride 524288 % 128 == 0) and walks rows
// row0, row0+4096, ... . Per iteration: wave-uniform token load, 16B gather,
// 2x sincos, 16B NT store. exp2f of the two frequencies hoisted out of the
// loop; the v==127 special case (cols 510/511 -> pe=0) is a loop-invariant
// uniform branch. unroll 4 -> 4 independent token->gather chains in flight.
__global__ __launch_bounds__(NTHR) void pe_gather_kernel(
    const int* __restrict__ token_ids,
    const vfloat4* __restrict__ emb,      // emb_table viewed as [VOCAB][128] float4
    vfloat4* __restrict__ out,            // [SEQ][128] float4
    int seq)                              // number of rows (131072)
{
    const int tid  = blockIdx.x * NTHR + threadIdx.x;
    const int v    = tid & 127;           // float4 column, loop-invariant
    const int row0 = tid >> 7;            // first row for this thread

    // loop-invariant frequencies
    const float w0 = exp2f(PE_C2 * (float)(2 * v));
    const float w1 = exp2f(PE_C2 * (float)(2 * v + 1));
    const bool  full = (v < 127);         // v==127: second pair is j=255 -> pe 0

    #pragma unroll 4
    for (int row = row0; row < seq; row += ROWS_PER_SWEEP) {
        const int tok = token_ids[row];
        const vfloat4 e = emb[(long long)tok * 128 + v];

        const float fi = (float)row;
        float s0, c0;
        __sincosf(fi * w0, &s0, &c0);

        vfloat4 r;
        r.x = e.x + s0;
        r.y = e.y + c0;

        if (full) {
            float s1, c1;
            __sincosf(fi * w1, &s1, &c1);
            r.z = e.z + s1;
            r.w = e.w + c1;
        } else {
            r.z = e.z;
            r.w = e.w;
        }

        __builtin_nontemporal_store(r, &out[(long long)row * 128 + v]);
    }
}

extern "C" void kernel_launch(void* const* d_in, const int* in_sizes, int n_in,
                              void* d_out, int out_size, void* d_ws, size_t ws_size,
                              hipStream_t stream) {
    const int*   token_ids = (const int*)d_in[0];
    const float* emb_table = (const float*)d_in[1];

    const int seq = in_sizes[0];          // 131072

    pe_gather_kernel<<<NBLK, NTHR, 0, stream>>>(
        token_ids, (const vfloat4*)emb_table, (vfloat4*)d_out, seq);
}